// Round 13
// baseline (562.517 us; speedup 1.0000x reference)
//
#include <hip/hip_runtime.h>

typedef unsigned int uint;
typedef unsigned short ushort;
typedef __attribute__((ext_vector_type(8))) short short8;
typedef __attribute__((ext_vector_type(16))) float f32x16;
typedef __attribute__((ext_vector_type(4))) uint uintx4;

#define T_STEPS 128
#define NGRP 128          // 2 replicas x 64 WGs

__device__ __forceinline__ ushort f2bf(float f) {
  union { float f; uint u; } v; v.f = f;
  uint r = v.u + 0x7fffu + ((v.u >> 16) & 1u);  // RNE
  return (ushort)(r >> 16);
}
__device__ __forceinline__ float bf2f(ushort u) {
  union { uint u; float f; } v; v.u = ((uint)u) << 16;
  return v.f;
}

union F8 { uint4 u4; short8 s; };
union F8v { uintx4 u; short8 s; };

// ---------------- init kernels ----------------

// xs f32 [64][128][512] -> xb bf16 blocked [128 t][64 kblk][64 row][8]
__global__ void convert_xs_kernel(const float* __restrict__ xs, ushort* __restrict__ xb) {
  int idx = blockIdx.x * 256 + threadIdx.x;   // 524288 granules
  int t = idx >> 12;
  int b = (idx >> 6) & 63;
  int j = idx & 63;                           // k-block
  const float* src = xs + (b * 128 + t) * 512 + j * 8;
  float4 a = *(const float4*)src;
  float4 c = *(const float4*)(src + 4);
  union { ushort r[8]; uint4 v; } p;
  p.r[0] = f2bf(a.x); p.r[1] = f2bf(a.y); p.r[2] = f2bf(a.z); p.r[3] = f2bf(a.w);
  p.r[4] = f2bf(c.x); p.r[5] = f2bf(c.y); p.r[6] = f2bf(c.z); p.r[7] = f2bf(c.w);
  *(uint4*)(xb + t * 32768 + j * 512 + b * 8) = p.v;
}

// W f32 [K][4096] -> WT bf16 [4096][1536] at k-offset ko (W_ih: ko=0, W_hh: ko=512)
__global__ void transpose_w_kernel(const float* __restrict__ W, ushort* __restrict__ WT, int ko) {
  __shared__ ushort tile[32][33];
  int kt = blockIdx.x * 32, nt = blockIdx.y * 32;
  int tx = threadIdx.x & 31, ty = threadIdx.x >> 5;
#pragma unroll
  for (int i = 0; i < 4; ++i) {
    int kk = ty + i * 8;
    tile[kk][tx] = f2bf(W[(kt + kk) * 4096 + nt + tx]);
  }
  __syncthreads();
#pragma unroll
  for (int i = 0; i < 4; ++i) {
    int nn = ty + i * 8;
    WT[(nt + nn) * 1536 + ko + kt + tx] = tile[tx][nn];
  }
}

// ---------------- persistent LSTM kernel ----------------
// 2 replicas x 64 WGs x 512 threads (8 waves). WG owns 16 units; M=32 rows;
// K split 8 ways across waves. Sync: sentinel-tagged data polling (round 9).
// NEW: double-buffered sP -> ONE barrier per step (sP-reuse guard removed;
// proof: finalize-t reads of buf A precede each wave's arrival at barrier
// t+1, and buf A is rewritten only after barrier t+1). Next-step x loads +
// x-MFMAs hoisted before the barrier (off the inter-WG critical path).

__global__ __launch_bounds__(512, 1) void lstm_persist(
    const ushort* __restrict__ xsb, const ushort* __restrict__ WT,
    const float* __restrict__ bias, const float* __restrict__ Wo,
    const float* __restrict__ bo, ushort* __restrict__ hbuf,
    uint* __restrict__ flg, float* __restrict__ out) {

  __shared__ float sP[2][8 * 2048];   // double-buffered [wv][nf][r][lane], 128KB

  const int tid = threadIdx.x;
  const int wg  = blockIdx.x;
  const int lane = tid & 63;
  const int wv = tid >> 6;         // wave id = K-slice (0..7)
  const int c  = lane & 31;        // fragment col / A-row
  const int hi = lane >> 5;
  const int rep = wg >> 6;         // replica: batch rows rep*32..rep*32+31
  const int wgu = wg & 63;         // unit-block: units wgu*16..wgu*16+15

  // ---- stationary weights (once): 2 N-frags x (4 x-kfrags + 8 h-kfrags) ----
  const int gc0 = ((c >> 4)) * 1024 + wgu * 16 + (c & 15);        // gates i/f
  const int gc1 = (2 + (c >> 4)) * 1024 + wgu * 16 + (c & 15);    // gates g/o
  uint4 Wx[4][2], Wh[8][2];
#pragma unroll
  for (int kf = 0; kf < 4; ++kf) {
    int k = wv * 64 + kf * 16 + hi * 8;
    Wx[kf][0] = *(const uint4*)(WT + gc0 * 1536 + k);
    Wx[kf][1] = *(const uint4*)(WT + gc1 * 1536 + k);
  }
#pragma unroll
  for (int i = 0; i < 8; ++i) {
    int k = 512 + (wv * 8 + i) * 16 + hi * 8;
    Wh[i][0] = *(const uint4*)(WT + gc0 * 1536 + k);
    Wh[i][1] = *(const uint4*)(WT + gc1 * 1536 + k);
  }

  const float bc0 = bias[gc0];
  const float bc1 = bias[gc1];
  const int r0f = wv * 2;          // finalize: this wave handles regs r0f, r0f+1
  float cst[2] = {0.f, 0.f};

  // ---- prologue: x-part for t=0 ----
  f32x16 acc0 = {}, acc1 = {};
  {
    const ushort* xst = xsb + rep * 256 + c * 8;
    uint4 Ax[4];
#pragma unroll
    for (int kf = 0; kf < 4; ++kf)
      Ax[kf] = *(const uint4*)(xst + (wv * 8 + kf * 2 + hi) * 512);
#pragma unroll
    for (int kf = 0; kf < 4; ++kf) {
      F8 a, w0, w1; a.u4 = Ax[kf]; w0.u4 = Wx[kf][0]; w1.u4 = Wx[kf][1];
      acc0 = __builtin_amdgcn_mfma_f32_32x32x16_bf16(a.s, w0.s, acc0, 0, 0, 0);
      acc1 = __builtin_amdgcn_mfma_f32_32x32x16_bf16(a.s, w1.s, acc1, 0, 0, 0);
    }
  }

  float* sPcur = &sP[0][0];
  float* sPnxt = &sP[1][0];

  for (int t = 0; t < T_STEPS; ++t) {
    const ushort* __restrict__ hrd = hbuf + t * 65536 + rep * 32768;
    ushort* __restrict__ hwr = hbuf + (t + 1) * 65536 + rep * 32768;

    // ---- issue next step's x loads early (latency hides under the poll) ----
    uint4 Ax[4];
    {
      const int tn = (t + 1) & 127;
      const ushort* xst = xsb + tn * 32768 + rep * 256 + c * 8;
#pragma unroll
      for (int kf = 0; kf < 4; ++kf)
        Ax[kf] = *(const uint4*)(xst + (wv * 8 + kf * 2 + hi) * 512);
    }

    // ---- h-part: poll-load the data itself (sentinel 0xFFFF = not ready) ----
    uintx4 Ah[8];
    {
      const ushort* hb = hrd + (wv * 8) * 512 + c * 16 + hi * 8;
      bool allok;
      do {
#pragma unroll
        for (int i = 0; i < 8; ++i)
          asm volatile("global_load_dwordx4 %0, %1, off sc1"
                       : "=v"(Ah[i]) : "v"(hb + i * 512) : "memory");
        asm volatile("s_waitcnt vmcnt(0)" ::: "memory");
        __builtin_amdgcn_sched_barrier(0);
        bool ok = true;
#pragma unroll
        for (int i = 0; i < 8; ++i)
          ok = ok && ((Ah[i].x & 0xFFFFu) != 0xFFFFu) && ((Ah[i].w >> 16) != 0xFFFFu);
        allok = __all(ok);
        if (!allok) __builtin_amdgcn_s_sleep(1);
      } while (!allok);
    }
#pragma unroll
    for (int i = 0; i < 8; ++i) {
      F8v a; F8 w0, w1; a.u = Ah[i]; w0.u4 = Wh[i][0]; w1.u4 = Wh[i][1];
      acc0 = __builtin_amdgcn_mfma_f32_32x32x16_bf16(a.s, w0.s, acc0, 0, 0, 0);
      acc1 = __builtin_amdgcn_mfma_f32_32x32x16_bf16(a.s, w1.s, acc1, 0, 0, 0);
    }

    // ---- partials to LDS buf cur (bank = lane: conflict-free) ----
    {
      float* p = sPcur + wv * 2048 + lane;
#pragma unroll
      for (int r = 0; r < 16; ++r) p[r * 64] = acc0[r];
#pragma unroll
      for (int r = 0; r < 16; ++r) p[1024 + r * 64] = acc1[r];
    }

    // ---- next step's x MFMAs (pre-barrier: off the inter-WG critical path) ----
    f32x16 accN0 = {}, accN1 = {};
#pragma unroll
    for (int kf = 0; kf < 4; ++kf) {
      F8 a, w0, w1; a.u4 = Ax[kf]; w0.u4 = Wx[kf][0]; w1.u4 = Wx[kf][1];
      accN0 = __builtin_amdgcn_mfma_f32_32x32x16_bf16(a.s, w0.s, accN0, 0, 0, 0);
      accN1 = __builtin_amdgcn_mfma_f32_32x32x16_bf16(a.s, w1.s, accN1, 0, 0, 0);
    }

    __syncthreads();   // partials[cur] complete (the ONLY barrier per step)

    // ---- finalize: reduce, gates, pack 16B granules, fire-and-forget store ----
#pragma unroll
    for (int s = 0; s < 2; ++s) {
      int r = r0f + s;
      int o = r * 64 + lane;
      float f0 = bc0, f1 = bc1;
#pragma unroll
      for (int w = 0; w < 8; ++w) {
        f0 += sPcur[w * 2048 + o];
        f1 += sPcur[w * 2048 + 1024 + o];
      }
      // unit u = c&15: i = f0@u, f = f0@(u+16), g = f1@u, o = f1@(u+16)
      float ff = __shfl_xor(f0, 16);
      float oo = __shfl_xor(f1, 16);
      float ig = 1.f / (1.f + __expf(-f0));
      float fg = 1.f / (1.f + __expf(-ff));
      float gg = fmaxf(f1, 0.f);
      float og = 1.f / (1.f + __expf(-oo));
      float cn = fg * cst[s] + ig * gg;
      cst[s] = cn;
      ushort hv = f2bf(og * fmaxf(cn, 0.f));   // h >= 0: never 0xFFFF
      // pack row's 16 units (lanes c<16) into 16B granules on lanes c in {0,8}
      int hvi = (int)(uint)hv;
      uint q0 = ((uint)hvi & 0xFFFFu) | ((uint)__shfl_xor(hvi, 1) << 16);
      uint q1 = (uint)__shfl_xor((int)q0, 2);
      uint q2 = (uint)__shfl_xor((int)q0, 4);
      uint q3 = (uint)__shfl_xor((int)q1, 4);
      if ((lane & 23) == 0) {   // lanes 0,8,32,40: granule (row(hi), half)
        int row = (r & 3) + 8 * (r >> 2) + 4 * hi;
        int half = (lane >> 3) & 1;
        uintx4 g; g.x = q0; g.y = q1; g.z = q2; g.w = q3;
        asm volatile("global_store_dwordx4 %0, %1, off sc1"
                     :: "v"(hwr + wgu * 512 + row * 16 + half * 8), "v"(g) : "memory");
      }
    }

    // ---- rotate: acc <- next-step x partial; swap sP buffers ----
    acc0 = accN0; acc1 = accN1;
    float* tmp = sPcur; sPcur = sPnxt; sPnxt = tmp;
  }

  // ---- final publish for out-GEMM (once): ack stores, then flag ----
  asm volatile("s_waitcnt vmcnt(0)" ::: "memory");
  __syncthreads();
  if (tid == 0)
    __hip_atomic_store(flg + (rep * 64 + wgu) * 32, 1u,
                       __ATOMIC_RELAXED, __HIP_MEMORY_SCOPE_AGENT);

  // ---- wait for own replica's final h, then out = h_T @ W_o + b_o ----
  if (tid < 64) {
    const uint* fp = flg + (rep * 64 + tid) * 32;
    while (__hip_atomic_load(fp, __ATOMIC_RELAXED, __HIP_MEMORY_SCOPE_AGENT) < 1u)
      __builtin_amdgcn_s_sleep(2);
  }
  __syncthreads();
  if (tid < 256) {
    int oidx = wg * 256 + tid;            // 0..32767
    int b = oidx >> 9, oc = oidx & 511;
    int rep2 = b >> 5, row = b & 31;
    const ushort* hf = hbuf + T_STEPS * 65536 + rep2 * 32768 + row * 16;
    float s = bo[oc];
#pragma unroll 2
    for (int w = 0; w < 64; ++w) {
      uint4 h0 = *(const uint4*)(hf + w * 512);
      uint4 h1 = *(const uint4*)(hf + w * 512 + 8);
      const ushort* p0 = (const ushort*)&h0;
      const ushort* p1 = (const ushort*)&h1;
#pragma unroll
      for (int j = 0; j < 8; ++j)
        s = fmaf(bf2f(p0[j]), Wo[(w * 16 + j) * 512 + oc], s);
#pragma unroll
      for (int j = 0; j < 8; ++j)
        s = fmaf(bf2f(p1[j]), Wo[(w * 16 + 8 + j) * 512 + oc], s);
    }
    out[oidx] = s;
  }
}

// ---------------- host launch ----------------

extern "C" void kernel_launch(void* const* d_in, const int* in_sizes, int n_in,
                              void* d_out, int out_size, void* d_ws, size_t ws_size,
                              hipStream_t stream) {
  (void)in_sizes; (void)n_in; (void)out_size; (void)ws_size;
  const float* xs  = (const float*)d_in[0];
  const float* Wih = (const float*)d_in[1];
  const float* Whh = (const float*)d_in[2];
  const float* b   = (const float*)d_in[3];
  const float* Wo  = (const float*)d_in[4];
  const float* bo  = (const float*)d_in[5];
  float* out = (float*)d_out;

  char* ws = (char*)d_ws;
  uint* flg    = (uint*)ws;                                  // 128 flags, 128B apart
  ushort* hbuf = (ushort*)(ws + 16384);                      // 129 x [2 rep][64 blk][32 row][16]
  ushort* xsb  = (ushort*)(ws + 16384 + 16908288);           // [128 t][64 kblk][64 row][8]
  ushort* WT   = (ushort*)(ws + 16384 + 16908288 + 8388608); // [4096][1536] bf16

  // every call (graph-safe): flags=0, h buffers=sentinel 0xFF, h_0=0
  hipMemsetAsync(ws, 0, 16384, stream);
  hipMemsetAsync(hbuf, 0xFF, 16908288, stream);
  hipMemsetAsync(hbuf, 0x00, 131072, stream);
  convert_xs_kernel<<<2048, 256, 0, stream>>>(xs, xsb);
  transpose_w_kernel<<<dim3(16, 128), 256, 0, stream>>>(Wih, WT, 0);
  transpose_w_kernel<<<dim3(32, 128), 256, 0, stream>>>(Whh, WT, 512);
  lstm_persist<<<NGRP, 512, 0, stream>>>(xsb, WT, b, Wo, bo, hbuf, flg, out);
}

// Round 14
// 406.777 us; speedup vs baseline: 1.3829x; 1.3829x over previous
//
#include <hip/hip_runtime.h>

typedef unsigned int uint;
typedef unsigned short ushort;
typedef __attribute__((ext_vector_type(8))) short short8;
typedef __attribute__((ext_vector_type(16))) float f32x16;
typedef __attribute__((ext_vector_type(4))) uint uintx4;

#define T_STEPS 128
#define NGRP 128          // 2 replicas x 64 WGs

__device__ __forceinline__ ushort f2bf(float f) {
  union { float f; uint u; } v; v.f = f;
  uint r = v.u + 0x7fffu + ((v.u >> 16) & 1u);  // RNE
  return (ushort)(r >> 16);
}
__device__ __forceinline__ float bf2f(ushort u) {
  union { uint u; float f; } v; v.u = ((uint)u) << 16;
  return v.f;
}

union F8 { uint4 u4; short8 s; };
union F8v { uintx4 u; short8 s; };

// ---------------- init kernels ----------------

// xs f32 [64][128][512] -> xb bf16 blocked [128 t][64 kblk][64 row][8]
__global__ void convert_xs_kernel(const float* __restrict__ xs, ushort* __restrict__ xb) {
  int idx = blockIdx.x * 256 + threadIdx.x;   // 524288 granules
  int t = idx >> 12;
  int b = (idx >> 6) & 63;
  int j = idx & 63;                           // k-block
  const float* src = xs + (b * 128 + t) * 512 + j * 8;
  float4 a = *(const float4*)src;
  float4 c = *(const float4*)(src + 4);
  union { ushort r[8]; uint4 v; } p;
  p.r[0] = f2bf(a.x); p.r[1] = f2bf(a.y); p.r[2] = f2bf(a.z); p.r[3] = f2bf(a.w);
  p.r[4] = f2bf(c.x); p.r[5] = f2bf(c.y); p.r[6] = f2bf(c.z); p.r[7] = f2bf(c.w);
  *(uint4*)(xb + t * 32768 + j * 512 + b * 8) = p.v;
}

// W f32 [K][4096] -> WT bf16 [4096][1536] at k-offset ko (W_ih: ko=0, W_hh: ko=512)
__global__ void transpose_w_kernel(const float* __restrict__ W, ushort* __restrict__ WT, int ko) {
  __shared__ ushort tile[32][33];
  int kt = blockIdx.x * 32, nt = blockIdx.y * 32;
  int tx = threadIdx.x & 31, ty = threadIdx.x >> 5;
#pragma unroll
  for (int i = 0; i < 4; ++i) {
    int kk = ty + i * 8;
    tile[kk][tx] = f2bf(W[(kt + kk) * 4096 + nt + tx]);
  }
  __syncthreads();
#pragma unroll
  for (int i = 0; i < 4; ++i) {
    int nn = ty + i * 8;
    WT[(nt + nn) * 1536 + ko + kt + tx] = tile[tx][nn];
  }
}

// ---------------- persistent LSTM kernel ----------------
// 2 replicas x 64 WGs x 512 threads (8 waves). WG owns 16 units; M=32 rows;
// K split 8 ways across waves. Sync: SENTINEL-TAGGED DATA POLLING —
// h buffers prefilled 0xFF; h >= 0 in bf16 can never be 0xFFFF; producers
// fire atomic 16B sc1 granule stores (no ack, no flag); consumers poll the
// data itself with L2-bypassing sc1 loads. One fabric trip per step.

__global__ __launch_bounds__(512, 1) void lstm_persist(
    const ushort* __restrict__ xsb, const ushort* __restrict__ WT,
    const float* __restrict__ bias, const float* __restrict__ Wo,
    const float* __restrict__ bo, ushort* __restrict__ hbuf,
    uint* __restrict__ flg, float* __restrict__ out) {

  __shared__ float sP[8 * 2 * 16 * 64];   // [wv][nf][r][lane] 64KB

  const int tid = threadIdx.x;
  const int wg  = blockIdx.x;
  const int lane = tid & 63;
  const int wv = tid >> 6;         // wave id = K-slice (0..7)
  const int c  = lane & 31;        // fragment col / A-row
  const int hi = lane >> 5;
  const int rep = wg >> 6;         // replica: batch rows rep*32..rep*32+31
  const int wgu = wg & 63;         // unit-block: units wgu*16..wgu*16+15

  // ---- stationary weights (once): 2 N-frags x (4 x-kfrags + 8 h-kfrags) ----
  const int gc0 = ((c >> 4)) * 1024 + wgu * 16 + (c & 15);        // gates i/f
  const int gc1 = (2 + (c >> 4)) * 1024 + wgu * 16 + (c & 15);    // gates g/o
  uint4 Wx[4][2], Wh[8][2];
#pragma unroll
  for (int kf = 0; kf < 4; ++kf) {
    int k = wv * 64 + kf * 16 + hi * 8;
    Wx[kf][0] = *(const uint4*)(WT + gc0 * 1536 + k);
    Wx[kf][1] = *(const uint4*)(WT + gc1 * 1536 + k);
  }
#pragma unroll
  for (int i = 0; i < 8; ++i) {
    int k = 512 + (wv * 8 + i) * 16 + hi * 8;
    Wh[i][0] = *(const uint4*)(WT + gc0 * 1536 + k);
    Wh[i][1] = *(const uint4*)(WT + gc1 * 1536 + k);
  }

  const float bc0 = bias[gc0];
  const float bc1 = bias[gc1];
  const int r0f = wv * 2;          // finalize: this wave handles regs r0f, r0f+1
  float cst[2] = {0.f, 0.f};

  for (int t = 0; t < T_STEPS; ++t) {
    const ushort* __restrict__ hrd = hbuf + t * 65536 + rep * 32768;
    ushort* __restrict__ hwr = hbuf + (t + 1) * 65536 + rep * 32768;

    // ---- x-part A loads + MFMAs (no dependence on other WGs) ----
    uint4 Ax[4];
    {
      const ushort* xst = xsb + t * 32768 + rep * 256 + c * 8;
#pragma unroll
      for (int kf = 0; kf < 4; ++kf)
        Ax[kf] = *(const uint4*)(xst + (wv * 8 + kf * 2 + hi) * 512);
    }
    f32x16 acc0 = {}, acc1 = {};
#pragma unroll
    for (int kf = 0; kf < 4; ++kf) {
      F8 a, w0, w1; a.u4 = Ax[kf]; w0.u4 = Wx[kf][0]; w1.u4 = Wx[kf][1];
      acc0 = __builtin_amdgcn_mfma_f32_32x32x16_bf16(a.s, w0.s, acc0, 0, 0, 0);
      acc1 = __builtin_amdgcn_mfma_f32_32x32x16_bf16(a.s, w1.s, acc1, 0, 0, 0);
    }

    // ---- h-part: poll-load the data itself (sentinel 0xFFFF = not ready) ----
    uintx4 Ah[8];
    {
      const ushort* hb = hrd + (wv * 8) * 512 + c * 16 + hi * 8;
      bool allok;
      do {
#pragma unroll
        for (int i = 0; i < 8; ++i)
          asm volatile("global_load_dwordx4 %0, %1, off sc1"
                       : "=v"(Ah[i]) : "v"(hb + i * 512) : "memory");
        asm volatile("s_waitcnt vmcnt(0)" ::: "memory");
        __builtin_amdgcn_sched_barrier(0);
        bool ok = true;
#pragma unroll
        for (int i = 0; i < 8; ++i)
          ok = ok && ((Ah[i].x & 0xFFFFu) != 0xFFFFu) && ((Ah[i].w >> 16) != 0xFFFFu);
        allok = __all(ok);
        if (!allok) __builtin_amdgcn_s_sleep(1);
      } while (!allok);
    }
#pragma unroll
    for (int i = 0; i < 8; ++i) {
      F8v a; F8 w0, w1; a.u = Ah[i]; w0.u4 = Wh[i][0]; w1.u4 = Wh[i][1];
      acc0 = __builtin_amdgcn_mfma_f32_32x32x16_bf16(a.s, w0.s, acc0, 0, 0, 0);
      acc1 = __builtin_amdgcn_mfma_f32_32x32x16_bf16(a.s, w1.s, acc1, 0, 0, 0);
    }

    // ---- partials to LDS (bank = lane: conflict-free) ----
    {
      float* p = sP + wv * 2048 + lane;
#pragma unroll
      for (int r = 0; r < 16; ++r) p[r * 64] = acc0[r];
#pragma unroll
      for (int r = 0; r < 16; ++r) p[1024 + r * 64] = acc1[r];
    }
    __syncthreads();

    // ---- finalize: reduce, gates, pack 16B granules, fire-and-forget store ----
#pragma unroll
    for (int s = 0; s < 2; ++s) {
      int r = r0f + s;
      int o = r * 64 + lane;
      float f0 = bc0, f1 = bc1;
#pragma unroll
      for (int w = 0; w < 8; ++w) {
        f0 += sP[w * 2048 + o];
        f1 += sP[w * 2048 + 1024 + o];
      }
      // unit u = c&15: i = f0@u, f = f0@(u+16), g = f1@u, o = f1@(u+16)
      float ff = __shfl_xor(f0, 16);
      float oo = __shfl_xor(f1, 16);
      float ig = 1.f / (1.f + __expf(-f0));
      float fg = 1.f / (1.f + __expf(-ff));
      float gg = fmaxf(f1, 0.f);
      float og = 1.f / (1.f + __expf(-oo));
      float cn = fg * cst[s] + ig * gg;
      cst[s] = cn;
      ushort hv = f2bf(og * fmaxf(cn, 0.f));   // h >= 0: never 0xFFFF
      // pack row's 16 units (lanes c<16) into 16B granules on lanes c in {0,8}
      int hvi = (int)(uint)hv;
      uint q0 = ((uint)hvi & 0xFFFFu) | ((uint)__shfl_xor(hvi, 1) << 16);
      uint q1 = (uint)__shfl_xor((int)q0, 2);
      uint q2 = (uint)__shfl_xor((int)q0, 4);
      uint q3 = (uint)__shfl_xor((int)q1, 4);
      if ((lane & 23) == 0) {   // lanes 0,8,32,40: granule (row(hi), half)
        int row = (r & 3) + 8 * (r >> 2) + 4 * hi;
        int half = (lane >> 3) & 1;
        uintx4 g; g.x = q0; g.y = q1; g.z = q2; g.w = q3;
        asm volatile("global_store_dwordx4 %0, %1, off sc1"
                     :: "v"(hwr + wgu * 512 + row * 16 + half * 8), "v"(g) : "memory");
      }
    }
    __syncthreads();   // sP reusable next iteration
  }

  // ---- final publish for out-GEMM (once): ack stores, then flag ----
  asm volatile("s_waitcnt vmcnt(0)" ::: "memory");
  __syncthreads();
  if (tid == 0)
    __hip_atomic_store(flg + (rep * 64 + wgu) * 32, 1u,
                       __ATOMIC_RELAXED, __HIP_MEMORY_SCOPE_AGENT);

  // ---- wait for own replica's final h, then out = h_T @ W_o + b_o ----
  if (tid < 64) {
    const uint* fp = flg + (rep * 64 + tid) * 32;
    while (__hip_atomic_load(fp, __ATOMIC_RELAXED, __HIP_MEMORY_SCOPE_AGENT) < 1u)
      __builtin_amdgcn_s_sleep(2);
  }
  __syncthreads();
  if (tid < 256) {
    int oidx = wg * 256 + tid;            // 0..32767
    int b = oidx >> 9, oc = oidx & 511;
    int rep2 = b >> 5, row = b & 31;
    const ushort* hf = hbuf + T_STEPS * 65536 + rep2 * 32768 + row * 16;
    float s = bo[oc];
#pragma unroll 2
    for (int w = 0; w < 64; ++w) {
      uint4 h0 = *(const uint4*)(hf + w * 512);
      uint4 h1 = *(const uint4*)(hf + w * 512 + 8);
      const ushort* p0 = (const ushort*)&h0;
      const ushort* p1 = (const ushort*)&h1;
#pragma unroll
      for (int j = 0; j < 8; ++j)
        s = fmaf(bf2f(p0[j]), Wo[(w * 16 + j) * 512 + oc], s);
#pragma unroll
      for (int j = 0; j < 8; ++j)
        s = fmaf(bf2f(p1[j]), Wo[(w * 16 + 8 + j) * 512 + oc], s);
    }
    out[oidx] = s;
  }
}

// ---------------- host launch ----------------

extern "C" void kernel_launch(void* const* d_in, const int* in_sizes, int n_in,
                              void* d_out, int out_size, void* d_ws, size_t ws_size,
                              hipStream_t stream) {
  (void)in_sizes; (void)n_in; (void)out_size; (void)ws_size;
  const float* xs  = (const float*)d_in[0];
  const float* Wih = (const float*)d_in[1];
  const float* Whh = (const float*)d_in[2];
  const float* b   = (const float*)d_in[3];
  const float* Wo  = (const float*)d_in[4];
  const float* bo  = (const float*)d_in[5];
  float* out = (float*)d_out;

  char* ws = (char*)d_ws;
  uint* flg    = (uint*)ws;                                  // 128 flags, 128B apart
  ushort* hbuf = (ushort*)(ws + 16384);                      // 129 x [2 rep][64 blk][32 row][16]
  ushort* xsb  = (ushort*)(ws + 16384 + 16908288);           // [128 t][64 kblk][64 row][8]
  ushort* WT   = (ushort*)(ws + 16384 + 16908288 + 8388608); // [4096][1536] bf16

  // every call (graph-safe): flags=0, h buffers=sentinel 0xFF, h_0=0
  hipMemsetAsync(ws, 0, 16384, stream);
  hipMemsetAsync(hbuf, 0xFF, 16908288, stream);
  hipMemsetAsync(hbuf, 0x00, 131072, stream);
  convert_xs_kernel<<<2048, 256, 0, stream>>>(xs, xsb);
  transpose_w_kernel<<<dim3(16, 128), 256, 0, stream>>>(Wih, WT, 0);
  transpose_w_kernel<<<dim3(32, 128), 256, 0, stream>>>(Whh, WT, 512);
  lstm_persist<<<NGRP, 512, 0, stream>>>(xsb, WT, b, Wo, bo, hbuf, flg, out);
}